// Round 1
// baseline (79.194 us; speedup 1.0000x reference)
//
#include <hip/hip_runtime.h>
#include <math.h>

#define NB 4096
#define NIN 128
#define NH 256
#define ND 32
#define NC 8
#define NK 256
#define NHS 16

// output offsets (in floats), concatenated in reference return order
#define OFF_KCHART 0
#define OFF_KCODE  4096
#define OFF_ZN     8192
#define OFF_ZTEX   (OFF_ZN + 4096*32)        // 139264
#define OFF_ROUTER (OFF_ZTEX + 4096*32)      // 270336
#define OFF_ZGEO   (OFF_ROUTER + 4096*8)     // 303104
#define OFF_LOSS   (OFF_ZGEO + 4096*32)      // 434176
#define OFF_IND    (OFF_LOSS + 1)            // 434177 (odd -> scalar access only)
#define OFF_ZNALL  (OFF_IND + 4096*8)        // 466945 (odd -> scalar access only)
#define OFF_CBAR   (OFF_ZNALL + 4096*8*32)   // 1515521
#define OFF_VLOC   (OFF_CBAR + 4096*32)      // 1646593 (odd -> scalar access only)

__device__ __forceinline__ float gelu_exact(float x) {
    // match jax.nn.gelu(approximate=False): x * (erf(x/sqrt(2)) + 1) / 2
    return x * (erff(x / 1.41421356237309504f) + 1.0f) * 0.5f;
}

// ---------------------------------------------------------------------------
// GEMM: out[M][N] = gelu(A[M][K] @ W[K][N] + b[N]); M=4096, N=256, K templated
// 64x64 tile, 256 threads, 4x4 microtile, BK=32
// ---------------------------------------------------------------------------
template<int K>
__global__ __launch_bounds__(256)
void gemm_bias_gelu(const float* __restrict__ A, const float* __restrict__ W,
                    const float* __restrict__ bias, float* __restrict__ out) {
    const int N = 256;
    __shared__ float sA[32][68];   // [k][row], stride 68 floats (272B, 16B-aligned)
    __shared__ float sB[32][68];   // [k][col]
    const int t  = threadIdx.x;
    const int n0 = blockIdx.x * 64;
    const int r0 = blockIdx.y * 64;
    const int ty = t >> 4, tx = t & 15;
    float acc[4][4];
    #pragma unroll
    for (int i = 0; i < 4; i++)
        #pragma unroll
        for (int j = 0; j < 4; j++) acc[i][j] = 0.f;

    for (int kk = 0; kk < K; kk += 32) {
        // A tile 64x32 -> sA[k][row]
        #pragma unroll
        for (int i = 0; i < 2; i++) {
            int id  = t + i * 256;           // 0..511
            int row = id >> 3, kq = id & 7;
            float4 a = *(const float4*)(A + (r0 + row) * K + kk + kq * 4);
            sA[kq * 4 + 0][row] = a.x;
            sA[kq * 4 + 1][row] = a.y;
            sA[kq * 4 + 2][row] = a.z;
            sA[kq * 4 + 3][row] = a.w;
        }
        // B tile 32x64 -> sB[k][col]
        #pragma unroll
        for (int i = 0; i < 2; i++) {
            int id   = t + i * 256;
            int krow = id >> 4, col4 = id & 15;
            float4 b = *(const float4*)(W + (kk + krow) * N + n0 + col4 * 4);
            *(float4*)(&sB[krow][col4 * 4]) = b;
        }
        __syncthreads();
        #pragma unroll
        for (int k = 0; k < 32; k++) {
            float4 av = *(const float4*)(&sA[k][ty * 4]);
            float4 bv = *(const float4*)(&sB[k][tx * 4]);
            float aa[4] = {av.x, av.y, av.z, av.w};
            float bb[4] = {bv.x, bv.y, bv.z, bv.w};
            #pragma unroll
            for (int i = 0; i < 4; i++)
                #pragma unroll
                for (int j = 0; j < 4; j++)
                    acc[i][j] = fmaf(aa[i], bb[j], acc[i][j]);
        }
        __syncthreads();
    }
    #pragma unroll
    for (int i = 0; i < 4; i++) {
        int row = r0 + ty * 4 + i;
        float4 o;
        float* op = (float*)&o;
        #pragma unroll
        for (int j = 0; j < 4; j++) {
            int col = n0 + tx * 4 + j;
            op[j] = gelu_exact(acc[i][j] + bias[col]);
        }
        *(float4*)(out + row * N + n0 + tx * 4) = o;
    }
}

// ---------------------------------------------------------------------------
// v = feats@Wv + bv ; scores ; softmax router ; K_chart ; c_bar ; v_local
// 16 rows/block, 256 threads (16 threads/row covering 2 cols each), grid 256
// ---------------------------------------------------------------------------
__global__ __launch_bounds__(256)
void router_kernel(const float* __restrict__ feats, const float* __restrict__ Wv,
                   const float* __restrict__ bv, const float* __restrict__ centers,
                   float* __restrict__ out, float* __restrict__ vloc_ws) {
    __shared__ float sWv[NH * ND];     // 32KB
    __shared__ float sCent[NC * ND];   // 1KB
    __shared__ float sV[16][ND + 1];
    __shared__ float sRout[16][NC];
    const int t = threadIdx.x;
    {
        const float4* w4 = (const float4*)Wv;
        float4* s4 = (float4*)sWv;
        #pragma unroll
        for (int i = 0; i < 8; i++) s4[t + i * 256] = w4[t + i * 256];
        if (t < 64) ((float4*)sCent)[t] = ((const float4*)centers)[t];
    }
    __syncthreads();
    const int r = t >> 4, cp = t & 15;
    const int row = blockIdx.x * 16 + r;
    const int c0 = cp * 2;
    float a0 = bv[c0], a1 = bv[c0 + 1];
    const float4* f4 = (const float4*)(feats + row * NH);
    for (int k4 = 0; k4 < NH / 4; k4++) {
        float4 f = f4[k4];
        a0 = fmaf(f.x, sWv[(k4 * 4 + 0) * ND + c0], a0);
        a1 = fmaf(f.x, sWv[(k4 * 4 + 0) * ND + c0 + 1], a1);
        a0 = fmaf(f.y, sWv[(k4 * 4 + 1) * ND + c0], a0);
        a1 = fmaf(f.y, sWv[(k4 * 4 + 1) * ND + c0 + 1], a1);
        a0 = fmaf(f.z, sWv[(k4 * 4 + 2) * ND + c0], a0);
        a1 = fmaf(f.z, sWv[(k4 * 4 + 2) * ND + c0 + 1], a1);
        a0 = fmaf(f.w, sWv[(k4 * 4 + 3) * ND + c0], a0);
        a1 = fmaf(f.w, sWv[(k4 * 4 + 3) * ND + c0 + 1], a1);
    }
    sV[r][c0] = a0; sV[r][c0 + 1] = a1;
    __syncthreads();
    if (t < 16) {
        const int rr = t, grow = blockIdx.x * 16 + rr;
        float sc[NC];
        float m = -3.4e38f; int kmax = 0;
        #pragma unroll
        for (int c = 0; c < NC; c++) {
            float acc = 0.f;
            #pragma unroll
            for (int k = 0; k < ND; k++) acc = fmaf(sV[rr][k], sCent[c * ND + k], acc);
            acc = acc / 5.65685424949238f;   // / sqrt(32)
            sc[c] = acc;
            if (acc > m) { m = acc; kmax = c; }
        }
        float s = 0.f;
        #pragma unroll
        for (int c = 0; c < NC; c++) { float e = expf(sc[c] - m); sc[c] = e; s += e; }
        float inv = 1.f / s;
        #pragma unroll
        for (int c = 0; c < NC; c++) {
            float rv = sc[c] * inv;
            sRout[rr][c] = rv;
            out[OFF_ROUTER + grow * NC + c] = rv;
        }
        out[OFF_KCHART + grow] = (float)kmax;
    }
    __syncthreads();
    #pragma unroll
    for (int j = 0; j < 2; j++) {
        int col = c0 + j;
        float cb = 0.f;
        #pragma unroll
        for (int c = 0; c < NC; c++) cb = fmaf(sRout[r][c], sCent[c * ND + col], cb);
        float vl = sV[r][col] - cb;
        out[OFF_CBAR + row * ND + col] = cb;
        out[OFF_VLOC + row * ND + col] = vl;
        vloc_ws[row * ND + col] = vl;
    }
}

// ---------------------------------------------------------------------------
// VQ argmin: per (row, chart) find argmin_k ||v_local - codebook[c][k]||^2
// block = 128 rows x 1 chart; 256 threads: lane r=t&63 owns rows r and r+64,
// tg=t>>6 scans a quarter of the 256 codes (codebook staged in LDS, broadcast)
// grid = 32 row-tiles * 8 charts = 256
// ---------------------------------------------------------------------------
__global__ __launch_bounds__(256)
void argmin_kernel(const float* __restrict__ codebook, const float* __restrict__ vloc_ws,
                   float* __restrict__ out) {
    __shared__ float sCB[NK * ND];   // 32KB
    __shared__ float sMin[4][128];
    __shared__ int   sIdx[4][128];
    const int t = threadIdx.x;
    const int c = blockIdx.x & 7;
    const int tile = blockIdx.x >> 3;   // 0..31
    const int row0 = tile * 128;
    {
        const float4* src = (const float4*)(codebook + c * NK * ND);
        float4* dst = (float4*)sCB;
        #pragma unroll
        for (int i = 0; i < 8; i++) dst[t + i * 256] = src[t + i * 256];
    }
    const int r = t & 63, tg = t >> 6;
    float vl0[ND], vl1[ND];
    {
        const float4* v0 = (const float4*)(vloc_ws + (row0 + r) * ND);
        const float4* v1 = (const float4*)(vloc_ws + (row0 + 64 + r) * ND);
        #pragma unroll
        for (int q = 0; q < 8; q++) {
            float4 a = v0[q];
            vl0[q*4] = a.x; vl0[q*4+1] = a.y; vl0[q*4+2] = a.z; vl0[q*4+3] = a.w;
            float4 b = v1[q];
            vl1[q*4] = b.x; vl1[q*4+1] = b.y; vl1[q*4+2] = b.z; vl1[q*4+3] = b.w;
        }
    }
    __syncthreads();
    float best0 = 3.4e38f, best1 = 3.4e38f;
    int bi0 = 0, bi1 = 0;
    for (int j = 0; j < 64; j++) {
        const int code = tg * 64 + j;
        const float4* e4 = (const float4*)(sCB + code * ND);
        float d0 = 0.f, d1 = 0.f;
        #pragma unroll
        for (int q = 0; q < 8; q++) {
            float4 e = e4[q];
            float x;
            x = vl0[q*4+0] - e.x; d0 = fmaf(x, x, d0);
            x = vl1[q*4+0] - e.x; d1 = fmaf(x, x, d1);
            x = vl0[q*4+1] - e.y; d0 = fmaf(x, x, d0);
            x = vl1[q*4+1] - e.y; d1 = fmaf(x, x, d1);
            x = vl0[q*4+2] - e.z; d0 = fmaf(x, x, d0);
            x = vl1[q*4+2] - e.z; d1 = fmaf(x, x, d1);
            x = vl0[q*4+3] - e.w; d0 = fmaf(x, x, d0);
            x = vl1[q*4+3] - e.w; d1 = fmaf(x, x, d1);
        }
        if (d0 < best0) { best0 = d0; bi0 = code; }
        if (d1 < best1) { best1 = d1; bi1 = code; }
    }
    sMin[tg][r] = best0;      sIdx[tg][r] = bi0;
    sMin[tg][r + 64] = best1; sIdx[tg][r + 64] = bi1;
    __syncthreads();
    if (t < 128) {
        float bb = sMin[0][t]; int ii = sIdx[0][t];
        #pragma unroll
        for (int g = 1; g < 4; g++) {
            float v = sMin[g][t]; int id = sIdx[g][t];
            if (v < bb) { bb = v; ii = id; }   // strict < keeps first occurrence
        }
        out[OFF_IND + (row0 + t) * NC + c] = (float)ii;
    }
}

// ---------------------------------------------------------------------------
// z_n_all + hyperbolic-distance loss partials
// block = 32 rows x 8 charts (one thread per pair), grid 128
// ---------------------------------------------------------------------------
__global__ __launch_bounds__(256)
void zn_loss_kernel(const float* __restrict__ codebook, const float* __restrict__ vloc_ws,
                    const float* __restrict__ Ws1, const float* __restrict__ bs1,
                    const float* __restrict__ Ws2, const float* __restrict__ bs2,
                    float* __restrict__ out, float* __restrict__ loss_partial) {
    __shared__ float sWs1[ND * NHS];
    __shared__ float sWs2[NHS * ND];
    __shared__ float sbs1[NHS], sbs2[ND];
    __shared__ float sRed[256];
    const int t = threadIdx.x;
    if (t < 128) ((float4*)sWs1)[t] = ((const float4*)Ws1)[t];
    else         ((float4*)sWs2)[t - 128] = ((const float4*)Ws2)[t - 128];
    if (t < NHS) sbs1[t] = bs1[t];
    else if (t < NHS + ND) sbs2[t - NHS] = bs2[t - NHS];
    __syncthreads();
    const int r = t >> 3;     // 0..31
    const int c = t & 7;
    const int row = blockIdx.x * 32 + r;
    float vl[ND];
    {
        const float4* v4 = (const float4*)(vloc_ws + row * ND);
        #pragma unroll
        for (int q = 0; q < 8; q++) {
            float4 a = v4[q];
            vl[q*4] = a.x; vl[q*4+1] = a.y; vl[q*4+2] = a.z; vl[q*4+3] = a.w;
        }
    }
    const int idx = (int)out[OFF_IND + row * NC + c];
    const float rc = out[OFF_ROUTER + row * NC + c];
    const float* zq = codebook + (c * NK + idx) * ND;
    float delta[ND], zqr[ND];
    #pragma unroll
    for (int k = 0; k < ND; k++) { float e = zq[k]; zqr[k] = e; delta[k] = vl[k] - e; }
    float s1[NHS];
    #pragma unroll
    for (int o = 0; o < NHS; o++) {
        float acc = sbs1[o];
        #pragma unroll
        for (int k = 0; k < ND; k++) acc = fmaf(delta[k], sWs1[k * NHS + o], acc);
        s1[o] = gelu_exact(acc);
    }
    float* znout = out + OFF_ZNALL + (row * NC + c) * ND;
    #pragma unroll
    for (int o = 0; o < ND; o++) {
        float acc = sbs2[o];
        #pragma unroll
        for (int k = 0; k < NHS; k++) acc = fmaf(s1[k], sWs2[k * ND + o], acc);
        znout[o] = acc;
    }
    // loss (d_cb == d_cm numerically; vq_loss = 1.25 * sum/B at the end)
    float vn2 = 0.f;
    #pragma unroll
    for (int k = 0; k < ND; k++) vn2 = fmaf(vl[k], vl[k], vn2);
    float norm = fmaxf(sqrtf(vn2), 1e-6f);
    float scale = fminf(0.99f / norm, 1.0f);
    float sq = 0.f, xn = 0.f, yn = 0.f;
    #pragma unroll
    for (int k = 0; k < ND; k++) {
        float yp = vl[k] * scale;
        float xp = zqr[k];
        float df = xp - yp;
        sq = fmaf(df, df, sq);
        xn = fmaf(xp, xp, xn);
        yn = fmaf(yp, yp, yn);
    }
    float denom = fmaxf((1.f - xn) * (1.f - yn), 1e-6f);
    float arg = fmaxf(1.f + 2.f * sq / denom, 1.f + 1e-6f);
    float d = acoshf(arg);
    sRed[t] = d * d * rc;
    __syncthreads();
    for (int s = 128; s > 0; s >>= 1) {
        if (t < s) sRed[t] += sRed[t + s];
        __syncthreads();
    }
    if (t == 0) loss_partial[blockIdx.x] = sRed[0];
}

// ---------------------------------------------------------------------------
// Finalize: z_n, z_tex, z_geo, K_code. block = 32 rows, thread=(row, 4 cols)
// ---------------------------------------------------------------------------
__global__ __launch_bounds__(256)
void finalize_kernel(const float* __restrict__ codebook, const float* __restrict__ vloc_ws,
                     float* __restrict__ out) {
    const int t = threadIdx.x;
    const int r = t >> 3;      // 0..31
    const int cg = t & 7;      // 4-col group
    const int row = blockIdx.x * 32 + r;
    float rout[NC]; int ind[NC];
    #pragma unroll
    for (int c = 0; c < NC; c++) {
        rout[c] = out[OFF_ROUTER + row * NC + c];
        ind[c]  = (int)out[OFF_IND + row * NC + c];
    }
    #pragma unroll
    for (int j = 0; j < 4; j++) {
        const int col = cg * 4 + j;
        float zn = 0.f, zqb = 0.f;
        #pragma unroll
        for (int c = 0; c < NC; c++) {
            zn  = fmaf(out[OFF_ZNALL + (row * NC + c) * ND + col], rout[c], zn);
            zqb = fmaf(codebook[(c * NK + ind[c]) * ND + col], rout[c], zqb);
        }
        float vl = vloc_ws[row * ND + col];
        float cb = out[OFF_CBAR + row * ND + col];
        out[OFF_ZN   + row * ND + col] = zn;
        out[OFF_ZTEX + row * ND + col] = vl - zqb - zn;
        out[OFF_ZGEO + row * ND + col] = cb + zqb + zn;   // c_bar + z_q_st + z_n
    }
    if (t < 32) {
        const int rr = blockIdx.x * 32 + t;
        int kc = (int)out[OFF_KCHART + rr];
        out[OFF_KCODE + rr] = out[OFF_IND + rr * NC + kc];
    }
}

__global__ __launch_bounds__(128)
void loss_reduce(const float* __restrict__ partials, float* __restrict__ out) {
    int t = threadIdx.x;
    float v = partials[t];
    #pragma unroll
    for (int off = 32; off > 0; off >>= 1) v += __shfl_down(v, off, 64);
    __shared__ float sTmp[2];
    if ((t & 63) == 0) sTmp[t >> 6] = v;
    __syncthreads();
    if (t == 0) out[OFF_LOSS] = 1.25f * (sTmp[0] + sTmp[1]) / 4096.f;
}

extern "C" void kernel_launch(void* const* d_in, const int* in_sizes, int n_in,
                              void* d_out, int out_size, void* d_ws, size_t ws_size,
                              hipStream_t stream) {
    const float* x        = (const float*)d_in[0];
    const float* W1       = (const float*)d_in[1];
    const float* b1       = (const float*)d_in[2];
    const float* W2       = (const float*)d_in[3];
    const float* b2       = (const float*)d_in[4];
    const float* Wv       = (const float*)d_in[5];
    const float* bv       = (const float*)d_in[6];
    const float* centers  = (const float*)d_in[7];
    const float* codebook = (const float*)d_in[8];
    const float* Ws1      = (const float*)d_in[9];
    const float* bs1      = (const float*)d_in[10];
    const float* Ws2      = (const float*)d_in[11];
    const float* bs2      = (const float*)d_in[12];
    float* out = (float*)d_out;
    float* ws  = (float*)d_ws;

    float* h1       = ws;                                // 4096*256
    float* feats    = ws + 4096 * 256;                   // 4096*256
    float* vloc     = ws + 2 * 4096 * 256;               // 4096*32
    float* partials = ws + 2 * 4096 * 256 + 4096 * 32;   // 128

    gemm_bias_gelu<128><<<dim3(4, 64), dim3(256), 0, stream>>>(x, W1, b1, h1);
    gemm_bias_gelu<256><<<dim3(4, 64), dim3(256), 0, stream>>>(h1, W2, b2, feats);
    router_kernel<<<dim3(256), dim3(256), 0, stream>>>(feats, Wv, bv, centers, out, vloc);
    argmin_kernel<<<dim3(256), dim3(256), 0, stream>>>(codebook, vloc, out);
    zn_loss_kernel<<<dim3(128), dim3(256), 0, stream>>>(codebook, vloc, Ws1, bs1, Ws2, bs2, out, partials);
    finalize_kernel<<<dim3(128), dim3(256), 0, stream>>>(codebook, vloc, out);
    loss_reduce<<<dim3(1), dim3(128), 0, stream>>>(partials, out);
}